// Round 14
// baseline (552.027 us; speedup 1.0000x reference)
//
#include <hip/hip_runtime.h>
#include <hip/hip_bf16.h>
#include <hip/hip_fp16.h>
#include <math.h>

// Problem constants (fixed by reference)
#define N_NODES   40000
#define F1        256        // F_IN
#define F2        512        // F_OUT2
#define NEDGE     320000
#define NB        4          // batch (graphs)
#define PROTS     10000      // nodes per graph
#define G1DIM     1028
#define G2DIM     32
#define NDRUGS    640
#define ZDIM      (G2DIM + NDRUGS)   // 672

// ---------------------------------------------------------------------------
// CSC build: in-degree count -> exclusive scan -> bucket fill
// ---------------------------------------------------------------------------
__global__ void zero_cnt_kernel(int* __restrict__ cnt) {
    int i = blockIdx.x * blockDim.x + threadIdx.x;
    if (i < N_NODES) cnt[i] = 0;
}

__global__ void count_kernel(const int* __restrict__ cols, int* __restrict__ cnt) {
    int e = blockIdx.x * blockDim.x + threadIdx.x;
    if (e < NEDGE) atomicAdd(&cnt[cols[e]], 1);
}

// single block, 1024 threads: exclusive scan of cnt -> offsets & cursor,
// dinv = rsqrt(cnt+1), zero the pool buffer
__global__ __launch_bounds__(1024)
void scan_dinv_kernel(const int* __restrict__ cnt, int* __restrict__ offsets,
                      int* __restrict__ cursor, float* __restrict__ dinv,
                      float* __restrict__ pool) {
    __shared__ int wsum[16];
    __shared__ int wpre[16];
    __shared__ int s_running;
    int t = threadIdx.x, lane = t & 63, wid = t >> 6;
    if (t == 0) s_running = 0;
    __syncthreads();
    for (int base = 0; base < N_NODES; base += 1024) {
        int i = base + t;
        int v = (i < N_NODES) ? cnt[i] : 0;
        if (i < N_NODES) dinv[i] = rsqrtf((float)v + 1.0f);
        // wave-inclusive scan
        int s = v;
#pragma unroll
        for (int off = 1; off < 64; off <<= 1) {
            int u = __shfl_up(s, off);
            if (lane >= off) s += u;
        }
        if (lane == 63) wsum[wid] = s;
        __syncthreads();
        if (t < 16) {
            int a = wsum[t];
            int p = a;
#pragma unroll
            for (int off = 1; off < 16; off <<= 1) {
                int u = __shfl_up(p, off);
                if (t >= off) p += u;
            }
            wpre[t] = p - a;   // exclusive across waves
        }
        __syncthreads();
        int excl = s_running + wpre[wid] + (s - v);
        if (i < N_NODES) { offsets[i] = excl; cursor[i] = excl; }
        __syncthreads();                 // all reads of s_running done
        if (t == 1023) s_running = excl + v;
        __syncthreads();
    }
    if (t == 0) offsets[N_NODES] = s_running;   // == NEDGE
    for (int i = t; i < NB * F2; i += 1024) pool[i] = 0.0f;
}

__global__ void fill_kernel(const int* __restrict__ rows, const int* __restrict__ cols,
                            int* __restrict__ cursor, int* __restrict__ row_sorted) {
    int e = blockIdx.x * blockDim.x + threadIdx.x;
    if (e < NEDGE) {
        int pos = atomicAdd(&cursor[cols[e]], 1);
        row_sorted[pos] = rows[e];
    }
}

// ---------------------------------------------------------------------------
// fp32 -> fp16 convert (vectorized: float4 in, 4 halfs = 8B out)
// ---------------------------------------------------------------------------
__global__ void f32_to_f16_kernel(const float* __restrict__ in, __half* __restrict__ out,
                                  int n4) {
    int i = blockIdx.x * blockDim.x + threadIdx.x;
    if (i >= n4) return;
    float4 v = ((const float4*)in)[i];
    __half2 h01 = __float22half2_rn(make_float2(v.x, v.y));
    __half2 h23 = __float22half2_rn(make_float2(v.z, v.w));
    uint2 u;
    u.x = *reinterpret_cast<unsigned int*>(&h01);
    u.y = *reinterpret_cast<unsigned int*>(&h23);
    ((uint2*)out)[i] = u;
}

// ---------------------------------------------------------------------------
// convert 16B of fp16 (8 features) to 8 floats
// ---------------------------------------------------------------------------
__device__ __forceinline__ void cvt8h(uint4 raw, float f[8]) {
    __half2 h0 = *reinterpret_cast<__half2*>(&raw.x);
    __half2 h1 = *reinterpret_cast<__half2*>(&raw.y);
    __half2 h2 = *reinterpret_cast<__half2*>(&raw.z);
    __half2 h3 = *reinterpret_cast<__half2*>(&raw.w);
    float2 f0 = __half22float2(h0);
    float2 f1 = __half22float2(h1);
    float2 f2 = __half22float2(h2);
    float2 f3 = __half22float2(h3);
    f[0] = f0.x; f[1] = f0.y; f[2] = f1.x; f[3] = f1.y;
    f[4] = f2.x; f[5] = f2.y; f[6] = f3.x; f[7] = f3.y;
}

// ---------------------------------------------------------------------------
// CSC gather (aggregation-first), fp16 rows, fp32 out. 4 nodes / 256-thr block.
// Wave w owns node c = blockIdx*4 + w. HALF-WAVE PAIRING: an fp16 row is
// 512B = 32 lanes x 16B, so lanes 0-31 load edge j's row while lanes 32-63
// load edge j+1's row (2 edges per memory instruction -> halved request
// count, the measured gather bottleneck). Per-lane acc[8]; one shfl_xor(32)
// merges the half-wave partials; self-term added after the merge.
//   out[c] = (src[c]*dinv[c] + sum_{r in N(c)} src[r]*dinv[r]) * dinv[c]
// ---------------------------------------------------------------------------
template <int C>
__global__ __launch_bounds__(256)
void gather_kernel(const __half* __restrict__ src, const float* __restrict__ dinv,
                   const int* __restrict__ offsets, const int* __restrict__ row_sorted,
                   float* __restrict__ out) {
    const int c    = blockIdx.x * 4 + (threadIdx.x >> 6);
    const int lane = threadIdx.x & 63;
    const int half = lane >> 5;       // which edge of the pair this lane serves
    const int fi   = lane & 31;       // 16B group = features [8*fi, 8*fi+8)
    const float dc = dinv[c];

    float acc[8];
#pragma unroll
    for (int k = 0; k < 8; ++k) acc[k] = 0.0f;

    const int beg = offsets[c], end = offsets[c + 1];
    int j = beg;
    float f[8];
    // 8 edges per iteration = 4 pair-loads in flight
    for (; j + 8 <= end; j += 8) {
        int r0 = row_sorted[j + 0 + half];
        int r1 = row_sorted[j + 2 + half];
        int r2 = row_sorted[j + 4 + half];
        int r3 = row_sorted[j + 6 + half];
        float d0 = dinv[r0], d1 = dinv[r1], d2 = dinv[r2], d3 = dinv[r3];
        uint4 a0 = ((const uint4*)(src + (size_t)r0 * C))[fi];
        uint4 a1 = ((const uint4*)(src + (size_t)r1 * C))[fi];
        uint4 a2 = ((const uint4*)(src + (size_t)r2 * C))[fi];
        uint4 a3 = ((const uint4*)(src + (size_t)r3 * C))[fi];
        cvt8h(a0, f);
#pragma unroll
        for (int k = 0; k < 8; ++k) acc[k] = fmaf(f[k], d0, acc[k]);
        cvt8h(a1, f);
#pragma unroll
        for (int k = 0; k < 8; ++k) acc[k] = fmaf(f[k], d1, acc[k]);
        cvt8h(a2, f);
#pragma unroll
        for (int k = 0; k < 8; ++k) acc[k] = fmaf(f[k], d2, acc[k]);
        cvt8h(a3, f);
#pragma unroll
        for (int k = 0; k < 8; ++k) acc[k] = fmaf(f[k], d3, acc[k]);
    }
    for (; j + 2 <= end; j += 2) {
        int r0 = row_sorted[j + half];
        float d0 = dinv[r0];
        uint4 a0 = ((const uint4*)(src + (size_t)r0 * C))[fi];
        cvt8h(a0, f);
#pragma unroll
        for (int k = 0; k < 8; ++k) acc[k] = fmaf(f[k], d0, acc[k]);
    }
    if (j < end) {                    // odd tail: half 1 contributes 0
        int r0 = row_sorted[j];
        float d0 = half ? 0.0f : dinv[r0];
        uint4 a0 = ((const uint4*)(src + (size_t)r0 * C))[fi];
        cvt8h(a0, f);
#pragma unroll
        for (int k = 0; k < 8; ++k) acc[k] = fmaf(f[k], d0, acc[k]);
    }

    // merge the two half-wave edge partials (lane i <-> lane i+32, same fi)
#pragma unroll
    for (int k = 0; k < 8; ++k) acc[k] += __shfl_xor(acc[k], 32, 64);

    // self term (identical in both halves; added AFTER merge -> counted once)
    uint4 sv = ((const uint4*)(src + (size_t)c * C))[fi];
    float s[8];
    cvt8h(sv, s);
    float o[8];
#pragma unroll
    for (int k = 0; k < 8; ++k) o[k] = fmaf(s[k], dc, acc[k]) * dc;

    // write: lane(half=0,fi) stores features 8fi..8fi+4, half=1 the next 4
    float4 w0 = make_float4(o[0], o[1], o[2], o[3]);
    float4 w1 = make_float4(o[4], o[5], o[6], o[7]);
    float4 wv = half ? w1 : w0;       // vector cndmask, no dynamic indexing
    *(float4*)(out + (size_t)c * C + fi * 8 + half * 4) = wv;
}

// ---------------------------------------------------------------------------
// fp32 tiled GEMM:  BM=64 BN=256 BK=16, 256 threads, 4x16 acc per thread.
// EPI=1: pool[g][n] max= relu(A@W + bias)    (layer-2, fused per-graph pool)
// EPI=2: Ch = fp16(relu(A@W + bias))         (layer-1, fp16+relu store)
// Requires M%64==0, N%256==0, K%16==0.
// ---------------------------------------------------------------------------
template <int EPI>
__global__ __launch_bounds__(256)
void gemm_kernel(const float* __restrict__ A, const float* __restrict__ W,
                 const float* __restrict__ bias, void* __restrict__ Cout,
                 unsigned int* __restrict__ pool, int M, int K, int N) {
    constexpr int BM = 64, BN = 256, BK = 16;
    __shared__ float As[BK][BM + 4];   // +4 pad keeps 16B align, breaks store conflicts
    __shared__ float Ws[BK][BN];

    const int t  = threadIdx.x;
    const int m0 = blockIdx.x * BM;
    const int n0 = blockIdx.y * BN;

    const int tr = (t >> 4) * 4;       // 4 output rows
    const int tc = (t & 15) * 4;       // cols tc + {0,64,128,192}

    float acc[4][16];
#pragma unroll
    for (int i = 0; i < 4; ++i)
#pragma unroll
        for (int j = 0; j < 16; ++j) acc[i][j] = 0.0f;

    // global load assignment
    const int la_row = t >> 2;          // 0..63
    const int la_col = (t & 3) * 4;     // 0,4,8,12
    const int lw_row = t >> 4;          // 0..15
    const int lw_col = (t & 15) * 4;    // 0..60 (+64/128/192)

    const float* Aptr = A + (size_t)(m0 + la_row) * K + la_col;
    const float* Wptr = W + (size_t)lw_row * N + n0 + lw_col;

    for (int k0 = 0; k0 < K; k0 += BK) {
        float4 av = *(const float4*)Aptr;  Aptr += BK;
        float4 wv0 = *(const float4*)(Wptr + 0);
        float4 wv1 = *(const float4*)(Wptr + 64);
        float4 wv2 = *(const float4*)(Wptr + 128);
        float4 wv3 = *(const float4*)(Wptr + 192);
        Wptr += (size_t)BK * N;

        As[la_col + 0][la_row] = av.x;
        As[la_col + 1][la_row] = av.y;
        As[la_col + 2][la_row] = av.z;
        As[la_col + 3][la_row] = av.w;
        *(float4*)&Ws[lw_row][lw_col +   0] = wv0;
        *(float4*)&Ws[lw_row][lw_col +  64] = wv1;
        *(float4*)&Ws[lw_row][lw_col + 128] = wv2;
        *(float4*)&Ws[lw_row][lw_col + 192] = wv3;
        __syncthreads();

#pragma unroll
        for (int k = 0; k < BK; ++k) {
            float4 a  = *(const float4*)&As[k][tr];
            float4 w0 = *(const float4*)&Ws[k][tc +   0];
            float4 w1 = *(const float4*)&Ws[k][tc +  64];
            float4 w2 = *(const float4*)&Ws[k][tc + 128];
            float4 w3 = *(const float4*)&Ws[k][tc + 192];
            float ar[4] = {a.x, a.y, a.z, a.w};
            float wr[16] = {w0.x, w0.y, w0.z, w0.w, w1.x, w1.y, w1.z, w1.w,
                            w2.x, w2.y, w2.z, w2.w, w3.x, w3.y, w3.z, w3.w};
#pragma unroll
            for (int i = 0; i < 4; ++i)
#pragma unroll
                for (int j = 0; j < 16; ++j)
                    acc[i][j] = fmaf(ar[i], wr[j], acc[i][j]);
        }
        __syncthreads();
    }

    // bias for this thread's 16 columns
    float bcol[16];
    {
        float4 b0 = *(const float4*)&bias[n0 + tc +   0];
        float4 b1 = *(const float4*)&bias[n0 + tc +  64];
        float4 b2 = *(const float4*)&bias[n0 + tc + 128];
        float4 b3 = *(const float4*)&bias[n0 + tc + 192];
        bcol[0]=b0.x; bcol[1]=b0.y; bcol[2]=b0.z; bcol[3]=b0.w;
        bcol[4]=b1.x; bcol[5]=b1.y; bcol[6]=b1.z; bcol[7]=b1.w;
        bcol[8]=b2.x; bcol[9]=b2.y; bcol[10]=b2.z; bcol[11]=b2.w;
        bcol[12]=b3.x; bcol[13]=b3.y; bcol[14]=b3.z; bcol[15]=b3.w;
    }

    if constexpr (EPI == 2) {
        // fp16 store with fused relu: r_h = fp16(relu(acc + bias))
        __half* Ch = (__half*)Cout;
#pragma unroll
        for (int i = 0; i < 4; ++i) {
            size_t row = (size_t)(m0 + tr + i);
            __half* cp = Ch + row * N + n0 + tc;
#pragma unroll
            for (int g = 0; g < 4; ++g) {
                float vx = fmaxf(acc[i][4*g + 0] + bcol[4*g + 0], 0.0f);
                float vy = fmaxf(acc[i][4*g + 1] + bcol[4*g + 1], 0.0f);
                float vz = fmaxf(acc[i][4*g + 2] + bcol[4*g + 2], 0.0f);
                float vw = fmaxf(acc[i][4*g + 3] + bcol[4*g + 3], 0.0f);
                __half2 h01 = __float22half2_rn(make_float2(vx, vy));
                __half2 h23 = __float22half2_rn(make_float2(vz, vw));
                uint2 u;
                u.x = *reinterpret_cast<unsigned int*>(&h01);
                u.y = *reinterpret_cast<unsigned int*>(&h23);
                *reinterpret_cast<uint2*>(cp + 64 * g) = u;
            }
        }
    } else {
        // EPI==1: fused per-graph max-pool of relu(acc + bias); block spans <=2 graphs
        __shared__ unsigned int red[2][BN];
        for (int i = t; i < 2 * BN; i += 256) red[i >> 8][i & 255] = 0u;
        __syncthreads();

        const int g_lo = m0 / PROTS;
        const int slot_first = (m0 + tr) / PROTS - g_lo;
        const int slot_last  = (m0 + tr + 3) / PROTS - g_lo;

        if (slot_first == slot_last) {
#pragma unroll
            for (int j = 0; j < 16; ++j) {
                float m = fmaxf(fmaxf(acc[0][j], acc[1][j]), fmaxf(acc[2][j], acc[3][j]));
                m = fmaxf(m + bcol[j], 0.0f);
                int lc = tc + (j >> 2) * 64 + (j & 3);
                atomicMax(&red[slot_first][lc], __float_as_uint(m));
            }
        } else {
#pragma unroll
            for (int i = 0; i < 4; ++i) {
                int slot = (m0 + tr + i) / PROTS - g_lo;
#pragma unroll
                for (int j = 0; j < 16; ++j) {
                    float m = fmaxf(acc[i][j] + bcol[j], 0.0f);
                    int lc = tc + (j >> 2) * 64 + (j & 3);
                    atomicMax(&red[slot][lc], __float_as_uint(m));
                }
            }
        }
        __syncthreads();

        const int straddle = ((m0 + BM - 1) / PROTS) != g_lo;
        for (int lc = t; lc < BN; lc += 256) {
            atomicMax(&pool[(size_t)g_lo * F2 + n0 + lc], red[0][lc]);
            if (straddle)
                atomicMax(&pool[(size_t)(g_lo + 1) * F2 + n0 + lc], red[1][lc]);
        }
    }
}

// ---------------------------------------------------------------------------
// g1 = relu(pool @ Wg1 + bg1)   [4,512]@[512,1028]
// ---------------------------------------------------------------------------
__global__ void mlpg1_kernel(const float* __restrict__ pool, const float* __restrict__ Wg1,
                             const float* __restrict__ bg1, float* __restrict__ out) {
    int idx = blockIdx.x * blockDim.x + threadIdx.x;
    if (idx >= NB * G1DIM) return;
    int b = idx / G1DIM, j = idx % G1DIM;
    const float* g = pool + b * F2;
    float s0 = 0.f, s1 = 0.f, s2 = 0.f, s3 = 0.f;
    for (int k = 0; k < F2; k += 4) {
        s0 = fmaf(g[k + 0], Wg1[(size_t)(k + 0) * G1DIM + j], s0);
        s1 = fmaf(g[k + 1], Wg1[(size_t)(k + 1) * G1DIM + j], s1);
        s2 = fmaf(g[k + 2], Wg1[(size_t)(k + 2) * G1DIM + j], s2);
        s3 = fmaf(g[k + 3], Wg1[(size_t)(k + 3) * G1DIM + j], s3);
    }
    out[idx] = fmaxf((s0 + s1) + (s2 + s3) + bg1[j], 0.0f);
}

// ---------------------------------------------------------------------------
// tail: g2 = g1@Wg2+bg2 ; z=[g2,DDI] ; f1=relu(z@Wf1+bf1) ;
//       f2=relu(f1@Wf2+bf2) ; out=sigmoid(f2@Wf3+bf3)      single block
// ---------------------------------------------------------------------------
__global__ __launch_bounds__(256)
void tail_kernel(const float* __restrict__ g1, const float* __restrict__ Wg2,
                 const float* __restrict__ bg2, const float* __restrict__ DDI,
                 const float* __restrict__ Wf1, const float* __restrict__ bf1,
                 const float* __restrict__ Wf2, const float* __restrict__ bf2,
                 const float* __restrict__ Wf3, const float* __restrict__ bf3,
                 float* __restrict__ out) {
    __shared__ float zs[NB][ZDIM + 8];
    __shared__ float f1s[NB][64];
    __shared__ float f2s[NB][16];
    int t = threadIdx.x;

    if (t < NB * G2DIM) {                      // 128 threads: g2
        int b = t >> 5, j = t & 31;
        float s0 = 0.f, s1 = 0.f, s2 = 0.f, s3 = 0.f;
        const float* gp = g1 + b * G1DIM;
        int k = 0;
        for (; k + 4 <= G1DIM; k += 4) {
            s0 = fmaf(gp[k + 0], Wg2[(size_t)(k + 0) * G2DIM + j], s0);
            s1 = fmaf(gp[k + 1], Wg2[(size_t)(k + 1) * G2DIM + j], s1);
            s2 = fmaf(gp[k + 2], Wg2[(size_t)(k + 2) * G2DIM + j], s2);
            s3 = fmaf(gp[k + 3], Wg2[(size_t)(k + 3) * G2DIM + j], s3);
        }
        for (; k < G1DIM; ++k) s0 = fmaf(gp[k], Wg2[(size_t)k * G2DIM + j], s0);
        zs[b][j] = (s0 + s1) + (s2 + s3) + bg2[j];
    }
    for (int i = t; i < NB * NDRUGS; i += 256) {
        int b = i / NDRUGS, k = i % NDRUGS;
        zs[b][G2DIM + k] = DDI[i];
    }
    __syncthreads();

    {   // f1: all 256 threads
        int b = t >> 6, j = t & 63;
        float s = bf1[j];
        for (int k = 0; k < ZDIM; ++k) s = fmaf(zs[b][k], Wf1[(size_t)k * 64 + j], s);
        f1s[b][j] = fmaxf(s, 0.0f);
    }
    __syncthreads();

    if (t < NB * 16) {
        int b = t >> 4, j = t & 15;
        float s = bf2[j];
#pragma unroll
        for (int k = 0; k < 64; ++k) s = fmaf(f1s[b][k], Wf2[k * 16 + j], s);
        f2s[b][j] = fmaxf(s, 0.0f);
    }
    __syncthreads();

    if (t < NB) {
        float s = bf3[0];
#pragma unroll
        for (int k = 0; k < 16; ++k) s = fmaf(f2s[t][k], Wf3[k], s);
        out[t] = 1.0f / (1.0f + expf(-s));
    }
}

// ---------------------------------------------------------------------------
// launch
// ---------------------------------------------------------------------------
extern "C" void kernel_launch(void* const* d_in, const int* in_sizes, int n_in,
                              void* d_out, int out_size, void* d_ws, size_t ws_size,
                              hipStream_t stream) {
    const float* x   = (const float*)d_in[0];
    const int*   ei  = (const int*)d_in[1];
    const float* DDI = (const float*)d_in[2];
    const float* W1  = (const float*)d_in[3];
    const float* b1  = (const float*)d_in[4];
    const float* W2  = (const float*)d_in[5];
    const float* b2  = (const float*)d_in[6];
    const float* Wg1 = (const float*)d_in[7];
    const float* bg1 = (const float*)d_in[8];
    const float* Wg2 = (const float*)d_in[9];
    const float* bg2 = (const float*)d_in[10];
    const float* Wf1 = (const float*)d_in[11];
    const float* bf1 = (const float*)d_in[12];
    const float* Wf2 = (const float*)d_in[13];
    const float* bf2 = (const float*)d_in[14];
    const float* Wf3 = (const float*)d_in[15];
    const float* bf3 = (const float*)d_in[16];
    float* out = (float*)d_out;

    const int* rows = ei;            // edge_index[0]
    const int* cols = ei + NEDGE;    // edge_index[1]

    // workspace layout
    char* ws = (char*)d_ws;
    const size_t MiB = 1024 * 1024;
    int*    cnt        = (int*)(ws + 0);            // 160 KB
    int*    offsets    = (int*)(ws + 256 * 1024);   // 160 KB (+1 elem)
    int*    cursor     = (int*)(ws + 512 * 1024);   // 160 KB
    float*  dinv       = (float*)(ws + 768 * 1024); // 160 KB
    int*    row_sorted = (int*)(ws + 1 * MiB);      // 1.28 MB
    float*  pool       = (float*)(ws + 2560 * 1024);// 8 KB
    float*  g1o        = (float*)(ws + 2664 * 1024);// 16.4 KB
    __half* x_h  = (__half*)(ws + 4 * MiB);         // 20.48 MB (ends ~24.5 MiB)
    float*  xa   = (float*)(ws + 26 * MiB);         // 40.96 MB (ends ~67 MiB)
    __half* r_h  = (__half*)(ws + 4 * MiB);         // reuses x_h region (dead after gather1)
    float*  ya   = (float*)(ws + 26 * MiB);         // reuses xa region (dead after gemm1)

    // CSC build (shared by both conv layers)
    zero_cnt_kernel<<<(N_NODES + 255) / 256, 256, 0, stream>>>(cnt);
    count_kernel<<<(NEDGE + 255) / 256, 256, 0, stream>>>(cols, cnt);
    scan_dinv_kernel<<<1, 1024, 0, stream>>>(cnt, offsets, cursor, dinv, pool);
    fill_kernel<<<(NEDGE + 255) / 256, 256, 0, stream>>>(rows, cols, cursor, row_sorted);

    // conv1, aggregation-first with fp16 gather operands:
    //   x_h = fp16(x) ; xa = A_hat x_h ; r_h = fp16(relu(xa@W1 + b1))
    f32_to_f16_kernel<<<(N_NODES * (F1 / 4) + 255) / 256, 256, 0, stream>>>(x, x_h, N_NODES * (F1 / 4));
    gather_kernel<F1><<<N_NODES / 4, 256, 0, stream>>>(x_h, dinv, offsets, row_sorted, xa);
    gemm_kernel<2><<<dim3(N_NODES / 64, F1 / 256), 256, 0, stream>>>(
        xa, W1, b1, (void*)r_h, nullptr, N_NODES, F1, F1);

    // conv2:  ya = A_hat r_h  (relu pre-applied) ;
    // pool[g][:] = max over rows of relu(ya@W2 + b2)   (fused epilogue)
    gather_kernel<F1><<<N_NODES / 4, 256, 0, stream>>>(r_h, dinv, offsets, row_sorted, ya);
    gemm_kernel<1><<<dim3(N_NODES / 64, F2 / 256), 256, 0, stream>>>(
        ya, W2, b2, nullptr, (unsigned int*)pool, N_NODES, F1, F2);

    // graph MLP + head
    mlpg1_kernel<<<(NB * G1DIM + 255) / 256, 256, 0, stream>>>(pool, Wg1, bg1, g1o);
    tail_kernel<<<1, 256, 0, stream>>>(g1o, Wg2, bg2, DDI, Wf1, bf1, Wf2, bf2, Wf3, bf3, out);
}